// Round 21
// baseline (97.586 us; speedup 1.0000x reference)
//
#include <hip/hip_runtime.h>

#define H_ 256
#define W_ 256
#define HW_ (H_*W_)

typedef __attribute__((ext_vector_type(8))) short bf16x8;
typedef __attribute__((ext_vector_type(4))) float f32x4;
typedef __attribute__((ext_vector_type(2))) float f32x2;

// ---- bf16 helpers ----------------------------------------------------------
__device__ __forceinline__ float bflo(unsigned u) { return __builtin_bit_cast(float, u << 16); }
__device__ __forceinline__ float bfhi(unsigned u) { return __builtin_bit_cast(float, u & 0xffff0000u); }
__device__ __forceinline__ unsigned f2bf(float f) {
    unsigned b = __builtin_bit_cast(unsigned, f);
    b += 0x7fffu + ((b >> 16) & 1u);
    return b >> 16;
}
__device__ __forceinline__ unsigned cvtpk(float lo, float hi) {
    unsigned r;
    asm("v_cvt_pk_bf16_f32 %0, %1, %2" : "=v"(r) : "v"(lo), "v"(hi));
    return r;
}
// channel pair {lo16, hi16} of one dword as packed f32x2 (feeds v_pk_fma_f32)
__device__ __forceinline__ f32x2 pair2(unsigned u) {
    f32x2 r;
    r[0] = bflo(u); r[1] = bfhi(u);
    return r;
}

// ---------------------------------------------------------------------------
// prep: all weights -> bf16 [k][o][c] tiles.
// ---------------------------------------------------------------------------
__global__ void prep_weights(const float* __restrict__ wdef, unsigned short* __restrict__ wdefb,
                             const float* __restrict__ wdc, unsigned short* __restrict__ wdcb,
                             const float* __restrict__ woff, unsigned short* __restrict__ woffb) {
    int idx = blockIdx.x * 256 + threadIdx.x;   // grid covers 36864
    if (idx < 36864) {
        int k = idx >> 12, o = (idx >> 6) & 63, c = idx & 63;
        wdefb[idx] = (unsigned short)f2bf(wdef[(o * 64 + c) * 9 + k]);
        wdcb[idx]  = (unsigned short)f2bf(wdc[(c * 64 + o) * 9 + (8 - k)]);
    }
    if (idx < 18432) {
        int k = idx >> 11, o = (idx >> 6) & 31, c = idx & 63;
        woffb[idx] = (o < 18) ? (unsigned short)f2bf(woff[(o * 64 + c) * 9 + k])
                              : (unsigned short)0;
    }
}

// ---------------------------------------------------------------------------
// x NCHW f32 -> xb NHWC bf16 (LDS transpose, 64px x 64c tiles)
// ---------------------------------------------------------------------------
__global__ __launch_bounds__(256) void x_to_nhwc(const float* __restrict__ x,
                                                 unsigned short* __restrict__ xb) {
    __shared__ unsigned short t[64 * 72];
    int tid = threadIdx.x;
    int b = blockIdx.x >> 10;
    long pxb = (long)(blockIdx.x & 1023) * 64;
    const float* xp = x + (long)b * 64 * HW_ + pxb;
    int px = tid & 63, cg = tid >> 6;
    for (int c = cg; c < 64; c += 4)
        t[px * 72 + c] = (unsigned short)f2bf(xp[(long)c * HW_ + px]);
    __syncthreads();
    int spx = tid >> 2, q = tid & 3;
    unsigned short* dst = xb + ((long)b * HW_ + pxb + spx) * 64 + q * 16;
    *(uint4*)dst       = *(const uint4*)&t[spx * 72 + q * 16];
    *(uint4*)(dst + 8) = *(const uint4*)&t[spx * 72 + q * 16 + 8];
}

// ---------------------------------------------------------------------------
// conv1 via MFMA, double-buffered pipelined staging (r13-exact).
// xb NHWC bf16 -> h NHWC bf16 (+bias+relu). Block 128px x 64o, 4 waves.
// ---------------------------------------------------------------------------
__global__ __launch_bounds__(256, 4) void conv1_mfma(const unsigned short* __restrict__ xb,
                                                     const unsigned short* __restrict__ wdcb,
                                                     const float* __restrict__ bias,
                                                     unsigned short* __restrict__ h) {
    __shared__ __align__(16) unsigned short sA[2][130 * 72];   // 37.4KB

    int tid = threadIdx.x;
    int linear = (blockIdx.x & 7) * 128 + (blockIdx.x >> 3);   // XCD swizzle, 1024 blocks
    int bx = linear & 1;
    int y  = (linear >> 1) & 255;
    int b  = linear >> 9;
    int X0 = bx * 128;

    int wave = tid >> 6, lane = tid & 63;
    int lr = lane & 15, lg = lane >> 4;
    int n0 = wave * 16;

    f32x4 acc[8];
#pragma unroll
    for (int m = 0; m < 8; ++m) { acc[m][0]=0.f; acc[m][1]=0.f; acc[m][2]=0.f; acc[m][3]=0.f; }

    const unsigned short* xbb = xb + (long)b * HW_ * 64;
    const unsigned short* pb  = wdcb + (n0 + lr) * 64 + lg * 8;

    int r0 = (y == 0) ? 1 : 0;
    int r1 = (y == H_ - 1) ? 1 : 2;

    uint4 L[5];
    auto LOADROW = [&](int yr) {
        const unsigned short* src = xbb + (long)yr * (W_ * 64);
#pragma unroll
        for (int t = 0; t < 5; ++t) {
            int e = tid + t * 256;
            uint4 v = { 0u, 0u, 0u, 0u };
            if (e < 1040) {
                int col = X0 - 1 + (e >> 3);
                if (col >= 0 && col < W_)
                    v = *(const uint4*)&src[(long)col * 64 + (e & 7) * 8];
            }
            L[t] = v;
        }
    };

    LOADROW(y + r0 - 1);
    int pa = 0;
    for (int ky = r0; ky <= r1; ++ky, ++pa) {
        unsigned short* buf = sA[pa & 1];
#pragma unroll
        for (int t = 0; t < 5; ++t) {           // ds_write staged regs
            int e = tid + t * 256;
            if (e < 1040) *(uint4*)&buf[(e >> 3) * 72 + (e & 7) * 8] = L[t];
        }
        if (ky < r1) LOADROW(y + ky);           // next row flies over MFMA
        asm volatile("s_waitcnt lgkmcnt(0)" ::: "memory");
        __builtin_amdgcn_s_barrier();
        asm volatile("" ::: "memory");
#pragma unroll
        for (int kx = 0; kx < 3; ++kx) {
            int k = ky * 3 + kx;
            bf16x8 b0 = *(const bf16x8*)(pb + k * 4096);
            bf16x8 b1 = *(const bf16x8*)(pb + k * 4096 + 32);
#pragma unroll
            for (int m = 0; m < 8; ++m) {
                const unsigned short* ap = &buf[(m * 16 + lr + kx) * 72 + lg * 8];
                bf16x8 a0 = *(const bf16x8*)ap;
                bf16x8 a1 = *(const bf16x8*)(ap + 32);
                acc[m] = __builtin_amdgcn_mfma_f32_16x16x32_bf16(a0, b0, acc[m], 0, 0, 0);
                acc[m] = __builtin_amdgcn_mfma_f32_16x16x32_bf16(a1, b1, acc[m], 0, 0, 0);
            }
        }
    }

    // epilogue: bias+relu, repack via LDS (sA[0]) to NHWC bf16
    __syncthreads();
    float bv = bias[n0 + lr];
    unsigned short* cs = sA[0];
#pragma unroll
    for (int m = 0; m < 8; ++m)
#pragma unroll
        for (int r = 0; r < 4; ++r) {
            float vv = fmaxf(acc[m][r] + bv, 0.f);
            cs[(m * 16 + lg * 4 + r) * 72 + n0 + lr] = (unsigned short)f2bf(vv);
        }
    __syncthreads();
    int spx = tid >> 1, sc0 = (tid & 1) * 32;
    unsigned short* dst = h + ((long)b * HW_ + (long)y * W_ + X0 + spx) * 64 + sc0;
    const unsigned short* srcp = &cs[spx * 72 + sc0];
#pragma unroll
    for (int q = 0; q < 4; ++q)
        *(uint4*)(dst + q * 8) = *(const uint4*)(srcp + q * 8);
}

// ---------------------------------------------------------------------------
// conv2 via MFMA, double-buffered pipelined staging, N=18 padded to 32
// (r13-exact). h NHWC bf16 -> off NCHW f32. Block 128px x 32o, 4 waves.
// ---------------------------------------------------------------------------
__global__ __launch_bounds__(256, 4) void conv2_mfma(const unsigned short* __restrict__ h,
                                                     const unsigned short* __restrict__ woffb,
                                                     const float* __restrict__ bias,
                                                     float* __restrict__ off) {
    __shared__ __align__(16) unsigned short sA[2][130 * 72];

    int tid = threadIdx.x;
    int linear = (blockIdx.x & 7) * 128 + (blockIdx.x >> 3);   // 1024 blocks
    int bx = linear & 1;
    int y  = (linear >> 1) & 255;
    int b  = linear >> 9;
    int X0 = bx * 128;

    int wave = tid >> 6, lane = tid & 63;
    int lr = lane & 15, lg = lane >> 4;
    int pxh = wave & 1, nh = wave >> 1;
    int n0 = nh * 16;
    int pxb = pxh * 64;

    f32x4 acc[4];
#pragma unroll
    for (int m = 0; m < 4; ++m) { acc[m][0]=0.f; acc[m][1]=0.f; acc[m][2]=0.f; acc[m][3]=0.f; }

    const unsigned short* hb = h + (long)b * HW_ * 64;
    const unsigned short* pb = woffb + (n0 + lr) * 64 + lg * 8;

    int r0 = (y == 0) ? 1 : 0;
    int r1 = (y == H_ - 1) ? 1 : 2;

    uint4 L[5];
    auto LOADROW = [&](int yr) {
        const unsigned short* src = hb + (long)yr * (W_ * 64);
#pragma unroll
        for (int t = 0; t < 5; ++t) {
            int e = tid + t * 256;
            uint4 v = { 0u, 0u, 0u, 0u };
            if (e < 1040) {
                int col = X0 - 1 + (e >> 3);
                if (col >= 0 && col < W_)
                    v = *(const uint4*)&src[(long)col * 64 + (e & 7) * 8];
            }
            L[t] = v;
        }
    };

    LOADROW(y + r0 - 1);
    int pa = 0;
    for (int ky = r0; ky <= r1; ++ky, ++pa) {
        unsigned short* buf = sA[pa & 1];
#pragma unroll
        for (int t = 0; t < 5; ++t) {
            int e = tid + t * 256;
            if (e < 1040) *(uint4*)&buf[(e >> 3) * 72 + (e & 7) * 8] = L[t];
        }
        if (ky < r1) LOADROW(y + ky);
        asm volatile("s_waitcnt lgkmcnt(0)" ::: "memory");
        __builtin_amdgcn_s_barrier();
        asm volatile("" ::: "memory");
#pragma unroll
        for (int kx = 0; kx < 3; ++kx) {
            int k = ky * 3 + kx;
            bf16x8 b0 = *(const bf16x8*)(pb + k * 2048);
            bf16x8 b1 = *(const bf16x8*)(pb + k * 2048 + 32);
#pragma unroll
            for (int m = 0; m < 4; ++m) {
                const unsigned short* ap = &buf[(pxb + m * 16 + lr + kx) * 72 + lg * 8];
                bf16x8 a0 = *(const bf16x8*)ap;
                bf16x8 a1 = *(const bf16x8*)(ap + 32);
                acc[m] = __builtin_amdgcn_mfma_f32_16x16x32_bf16(a0, b0, acc[m], 0, 0, 0);
                acc[m] = __builtin_amdgcn_mfma_f32_16x16x32_bf16(a1, b1, acc[m], 0, 0, 0);
            }
        }
    }

    int o = n0 + lr;
    if (o < 18) {
        float bv = bias[o];
        float* op = off + ((long)b * 18 + o) * HW_ + (long)y * W_ + X0 + pxb;
#pragma unroll
        for (int m = 0; m < 4; ++m) {
            float4 r = { acc[m][0] + bv, acc[m][1] + bv, acc[m][2] + bv, acc[m][3] + bv };
            *(float4*)(op + m * 16 + lg * 4) = r;
        }
    }
}

// ---------------------------------------------------------------------------
// deform conv via MFMA — PAIR-PHASE: 2 taps per barrier (phases 9 -> 5).
// Gathers for both taps issued back-to-back (S1 latency hides under
// interp(S0)); one lgkm-only barrier per phase; 16 MFMAs per phase.
// val = 4 buffers (2 phase-parities x 2 taps, 32 KB); overwrite of phase p's
// buffers by phase p+2 is fenced by phase p+1's barrier (reads complete
// before barrier arrival since MFMA consumes the ds_read data).
// Weights loaded at loop-top (oldest VMEM). pk_fma interp. (256,4).
// ---------------------------------------------------------------------------
struct Pass16 {
    uint4 a00, a01, a10, a11;   // corners, chans c0..c0+8
    uint4 b00, b01, b10, b11;   // corners, chans c0+8..c0+16
    float w00, w01, w10, w11;
};

__device__ __forceinline__ Pass16 issue16(const unsigned short* __restrict__ hb,
                                          int k, int y, int px, float dy, float dx, int c0) {
    Pass16 s;
    float py  = (float)(y - 1 + k / 3) + dy;
    float pxs = (float)(px - 1 + k % 3) + dx;
    float y0f = floorf(py), x0f = floorf(pxs);
    int iy0 = (int)y0f, ix0 = (int)x0f;
    float wy1 = py - y0f, wx1 = pxs - x0f;
    float wy0 = 1.f - wy1, wx0 = 1.f - wx1;
    bool vy0 = (iy0 >= 0) && (iy0 < H_);
    bool vy1 = (iy0 >= -1) && (iy0 < H_ - 1);
    bool vx0 = (ix0 >= 0) && (ix0 < W_);
    bool vx1 = (ix0 >= -1) && (ix0 < W_ - 1);
    int cy0 = min(max(iy0, 0), H_ - 1), cy1 = min(max(iy0 + 1, 0), H_ - 1);
    int cx0 = min(max(ix0, 0), W_ - 1), cx1 = min(max(ix0 + 1, 0), W_ - 1);
    s.w00 = wy0 * wx0 * ((vy0 && vx0) ? 1.f : 0.f);
    s.w01 = wy0 * wx1 * ((vy0 && vx1) ? 1.f : 0.f);
    s.w10 = wy1 * wx0 * ((vy1 && vx0) ? 1.f : 0.f);
    s.w11 = wy1 * wx1 * ((vy1 && vx1) ? 1.f : 0.f);
    int r00 = (cy0 * W_ + cx0) * 64 + c0, r01 = (cy0 * W_ + cx1) * 64 + c0;
    int r10 = (cy1 * W_ + cx0) * 64 + c0, r11 = (cy1 * W_ + cx1) * 64 + c0;
    s.a00 = *(const uint4*)&hb[r00];     s.a01 = *(const uint4*)&hb[r01];
    s.a10 = *(const uint4*)&hb[r10];     s.a11 = *(const uint4*)&hb[r11];
    s.b00 = *(const uint4*)&hb[r00 + 8]; s.b01 = *(const uint4*)&hb[r01 + 8];
    s.b10 = *(const uint4*)&hb[r10 + 8]; s.b11 = *(const uint4*)&hb[r11 + 8];
    return s;
}

__device__ __forceinline__ uint4 interp8p(uint4 q0, uint4 q1, uint4 q2, uint4 q3,
                                          f32x2 w00, f32x2 w01, f32x2 w10, f32x2 w11) {
    const unsigned* u0 = (const unsigned*)&q0;
    const unsigned* u1 = (const unsigned*)&q1;
    const unsigned* u2 = (const unsigned*)&q2;
    const unsigned* u3 = (const unsigned*)&q3;
    unsigned r[4];
#pragma unroll
    for (int j = 0; j < 4; ++j) {
        f32x2 v = pair2(u0[j]) * w00;                        // v_pk_mul_f32
        v = __builtin_elementwise_fma(pair2(u1[j]), w01, v); // v_pk_fma_f32
        v = __builtin_elementwise_fma(pair2(u2[j]), w10, v);
        v = __builtin_elementwise_fma(pair2(u3[j]), w11, v);
        r[j] = cvtpk(v[0], v[1]);
    }
    uint4 u = { r[0], r[1], r[2], r[3] };
    return u;
}

__global__ __launch_bounds__(256, 4) void deform_mfma(const unsigned short* __restrict__ h,
                                                      const float* __restrict__ off,
                                                      const unsigned short* __restrict__ wdefb,
                                                      const float* __restrict__ bias,
                                                      float* __restrict__ out) {
    __shared__ __align__(16) unsigned short val[2][2][64 * 64];   // 32KB: parity x tap

    int tid = threadIdx.x;
    int linear = (blockIdx.x & 7) * 256 + (blockIdx.x >> 3);   // 2048 blocks, XCD swizzle
    int b  = linear >> 10;
    int y  = (linear >> 2) & 255;
    int x0 = (linear & 3) * 64;

    int lane = tid & 63, wave = tid >> 6;
    int lr = lane & 15, lg = lane >> 4;
    int n0 = wave * 16;
    int gpx = tid >> 2;            // gather px 0..63 (channel-major: 4 lanes/pixel)
    int gc  = tid & 3;             // 16-chan chunk
    int c0  = gc * 16;
    int gx  = x0 + gpx;

    f32x4 acc[4];
#pragma unroll
    for (int m = 0; m < 4; ++m) { acc[m][0]=0.f; acc[m][1]=0.f; acc[m][2]=0.f; acc[m][3]=0.f; }

    const unsigned short* hb   = h + (long)b * HW_ * 64;
    const float* ofb  = off + (long)b * 18 * HW_ + y * W_ + gx;
    const unsigned short* bsrc = wdefb + (n0 + lr) * 64 + lg * 8;

    // prologue: offsets for taps 0,1
    float dyA = ofb[0],        dxA = ofb[HW_];
    float dyB = ofb[2 * HW_],  dxB = ofb[3 * HW_];

    // swizzled LDS slots (shorts): slot index 0..7 within a 128B px row
    int slotL = ((2 * gc)     ^ (gpx & 7)) * 8;
    int slotH = ((2 * gc + 1) ^ (gpx & 7)) * 8;
    int rdL   = ((lg)     ^ (lr & 7)) * 8;
    int rdH   = ((lg + 4) ^ (lr & 7)) * 8;

    for (int kp = 0; kp < 9; kp += 2) {
        int pb = (kp >> 1) & 1;
        bool has2 = (kp + 1 < 9);

        // weights for both taps — issued FIRST (oldest VMEM), so MFMA's
        // implicit vmcnt wait drains only weights, never the gathers.
        bf16x8 bc0 = *(const bf16x8*)(bsrc + kp * 4096);
        bf16x8 bc1 = *(const bf16x8*)(bsrc + kp * 4096 + 32);
        bf16x8 bd0 = bc0, bd1 = bc1;
        if (has2) {
            bd0 = *(const bf16x8*)(bsrc + (kp + 1) * 4096);
            bd1 = *(const bf16x8*)(bsrc + (kp + 1) * 4096 + 32);
        }

        // gathers for both taps, back-to-back (S1 flies under interp(S0))
        Pass16 S0 = issue16(hb, kp, y, gx, dyA, dxA, c0);
        Pass16 S1;
        if (has2) S1 = issue16(hb, kp + 1, y, gx, dyB, dxB, c0);

        // next pair's offsets
        float dyn0 = 0.f, dxn0 = 0.f, dyn1 = 0.f, dxn1 = 0.f;
        if (kp + 2 < 9) { dyn0 = ofb[(2 * kp + 4) * HW_]; dxn0 = ofb[(2 * kp + 5) * HW_]; }
        if (kp + 3 < 9) { dyn1 = ofb[(2 * kp + 6) * HW_]; dxn1 = ofb[(2 * kp + 7) * HW_]; }

        // interp both taps -> swizzled LDS (pk_fma)
        {
            f32x2 w00 = { S0.w00, S0.w00 }, w01 = { S0.w01, S0.w01 };
            f32x2 w10 = { S0.w10, S0.w10 }, w11 = { S0.w11, S0.w11 };
            unsigned short* vb = val[pb][0];
            *(uint4*)&vb[gpx * 64 + slotL] = interp8p(S0.a00, S0.a01, S0.a10, S0.a11,
                                                      w00, w01, w10, w11);
            *(uint4*)&vb[gpx * 64 + slotH] = interp8p(S0.b00, S0.b01, S0.b10, S0.b11,
                                                      w00, w01, w10, w11);
        }
        if (has2) {
            f32x2 w00 = { S1.w00, S1.w00 }, w01 = { S1.w01, S1.w01 };
            f32x2 w10 = { S1.w10, S1.w10 }, w11 = { S1.w11, S1.w11 };
            unsigned short* vb = val[pb][1];
            *(uint4*)&vb[gpx * 64 + slotL] = interp8p(S1.a00, S1.a01, S1.a10, S1.a11,
                                                      w00, w01, w10, w11);
            *(uint4*)&vb[gpx * 64 + slotH] = interp8p(S1.b00, S1.b01, S1.b10, S1.b11,
                                                      w00, w01, w10, w11);
        }

        asm volatile("s_waitcnt lgkmcnt(0)" ::: "memory");  // my ds_writes committed
        __builtin_amdgcn_s_barrier();                       // vmcnt NOT drained
        asm volatile("" ::: "memory");                      // keep ds_reads below barrier

        __builtin_amdgcn_s_setprio(1);
        {
            const unsigned short* vb = val[pb][0];
#pragma unroll
            for (int m = 0; m < 4; ++m) {
                const unsigned short* ap = &vb[(m * 16 + lr) * 64];
                bf16x8 a0 = *(const bf16x8*)&ap[rdL];
                bf16x8 a1 = *(const bf16x8*)&ap[rdH];
                acc[m] = __builtin_amdgcn_mfma_f32_16x16x32_bf16(a0, bc0, acc[m], 0, 0, 0);
                acc[m] = __builtin_amdgcn_mfma_f32_16x16x32_bf16(a1, bc1, acc[m], 0, 0, 0);
            }
        }
        if (has2) {
            const unsigned short* vb = val[pb][1];
#pragma unroll
            for (int m = 0; m < 4; ++m) {
                const unsigned short* ap = &vb[(m * 16 + lr) * 64];
                bf16x8 a0 = *(const bf16x8*)&ap[rdL];
                bf16x8 a1 = *(const bf16x8*)&ap[rdH];
                acc[m] = __builtin_amdgcn_mfma_f32_16x16x32_bf16(a0, bd0, acc[m], 0, 0, 0);
                acc[m] = __builtin_amdgcn_mfma_f32_16x16x32_bf16(a1, bd1, acc[m], 0, 0, 0);
            }
        }
        __builtin_amdgcn_s_setprio(0);

        dyA = dyn0; dxA = dxn0; dyB = dyn1; dxB = dxn1;
    }

    // epilogue: D col=lane&15 -> o = n0+lr; row -> px = m*16+lg*4+r
    float bv = bias[n0 + lr];
    float* outb = out + ((long)b * 64 + n0 + lr) * HW_ + y * W_ + x0;
#pragma unroll
    for (int m = 0; m < 4; ++m) {
        float4 r = { fmaxf(acc[m][0] + bv, 0.f), fmaxf(acc[m][1] + bv, 0.f),
                     fmaxf(acc[m][2] + bv, 0.f), fmaxf(acc[m][3] + bv, 0.f) };
        *(float4*)(outb + m * 16 + lg * 4) = r;
    }
}

// ---------------------------------------------------------------------------
extern "C" void kernel_launch(void* const* d_in, const int* in_sizes, int n_in,
                              void* d_out, int out_size, void* d_ws, size_t ws_size,
                              hipStream_t stream) {
    const float* x        = (const float*)d_in[0];
    const float* w_deconv = (const float*)d_in[1];
    const float* b_deconv = (const float*)d_in[2];
    const float* w_off    = (const float*)d_in[3];
    const float* b_off    = (const float*)d_in[4];
    const float* w_def    = (const float*)d_in[5];
    const float* b_def    = (const float*)d_in[6];
    float* out = (float*)d_out;

    char* ws = (char*)d_ws;
    unsigned short* xbb   = (unsigned short*)ws;               // 16,777,216 B
    unsigned short* hbf   = (unsigned short*)(ws + 16777216);  // 16,777,216 B
    float* offset         = (float*)(ws + 33554432);           //  9,437,184 B
    unsigned short* wdcb  = (unsigned short*)(ws + 42991616);  //     73,728 B
    unsigned short* wdefb = (unsigned short*)(ws + 43065344);  //     73,728 B
    unsigned short* woffb = (unsigned short*)(ws + 43139072);  //     36,864 B

    prep_weights<<<144, 256, 0, stream>>>(w_def, wdefb, w_deconv, wdcb, w_off, woffb);
    x_to_nhwc<<<2048, 256, 0, stream>>>(x, xbb);
    conv1_mfma<<<1024, 256, 0, stream>>>(xbb, wdcb, b_deconv, hbf);
    conv2_mfma<<<1024, 256, 0, stream>>>(hbf, woffb, b_off, offset);
    deform_mfma<<<2048, 256, 0, stream>>>(hbf, offset, wdefb, b_def, out);
}

// Round 22
// 95.214 us; speedup vs baseline: 1.0249x; 1.0249x over previous
//
#include <hip/hip_runtime.h>

#define H_ 256
#define W_ 256
#define HW_ (H_*W_)

typedef __attribute__((ext_vector_type(8))) short bf16x8;
typedef __attribute__((ext_vector_type(4))) float f32x4;

// ---- bf16 helpers ----------------------------------------------------------
__device__ __forceinline__ float bflo(unsigned u) { return __builtin_bit_cast(float, u << 16); }
__device__ __forceinline__ float bfhi(unsigned u) { return __builtin_bit_cast(float, u & 0xffff0000u); }
__device__ __forceinline__ unsigned f2bf(float f) {
    unsigned b = __builtin_bit_cast(unsigned, f);
    b += 0x7fffu + ((b >> 16) & 1u);
    return b >> 16;
}
__device__ __forceinline__ unsigned cvtpk(float lo, float hi) {
    unsigned r;
    asm("v_cvt_pk_bf16_f32 %0, %1, %2" : "=v"(r) : "v"(lo), "v"(hi));
    return r;
}
__device__ __forceinline__ void unpack8(uint4 v, float* f) {
    f[0] = bflo(v.x); f[1] = bfhi(v.x); f[2] = bflo(v.y); f[3] = bfhi(v.y);
    f[4] = bflo(v.z); f[5] = bfhi(v.z); f[6] = bflo(v.w); f[7] = bfhi(v.w);
}

// ---------------------------------------------------------------------------
// prep: all weights -> bf16 [k][o][c] tiles.
// ---------------------------------------------------------------------------
__global__ void prep_weights(const float* __restrict__ wdef, unsigned short* __restrict__ wdefb,
                             const float* __restrict__ wdc, unsigned short* __restrict__ wdcb,
                             const float* __restrict__ woff, unsigned short* __restrict__ woffb) {
    int idx = blockIdx.x * 256 + threadIdx.x;   // grid covers 36864
    if (idx < 36864) {
        int k = idx >> 12, o = (idx >> 6) & 63, c = idx & 63;
        wdefb[idx] = (unsigned short)f2bf(wdef[(o * 64 + c) * 9 + k]);
        wdcb[idx]  = (unsigned short)f2bf(wdc[(c * 64 + o) * 9 + (8 - k)]);
    }
    if (idx < 18432) {
        int k = idx >> 11, o = (idx >> 6) & 31, c = idx & 63;
        woffb[idx] = (o < 18) ? (unsigned short)f2bf(woff[(o * 64 + c) * 9 + k])
                              : (unsigned short)0;
    }
}

// ---------------------------------------------------------------------------
// x NCHW f32 -> xb NHWC bf16 (LDS transpose, 64px x 64c tiles)
// ---------------------------------------------------------------------------
__global__ __launch_bounds__(256) void x_to_nhwc(const float* __restrict__ x,
                                                 unsigned short* __restrict__ xb) {
    __shared__ unsigned short t[64 * 72];
    int tid = threadIdx.x;
    int b = blockIdx.x >> 10;
    long pxb = (long)(blockIdx.x & 1023) * 64;
    const float* xp = x + (long)b * 64 * HW_ + pxb;
    int px = tid & 63, cg = tid >> 6;
    for (int c = cg; c < 64; c += 4)
        t[px * 72 + c] = (unsigned short)f2bf(xp[(long)c * HW_ + px]);
    __syncthreads();
    int spx = tid >> 2, q = tid & 3;
    unsigned short* dst = xb + ((long)b * HW_ + pxb + spx) * 64 + q * 16;
    *(uint4*)dst       = *(const uint4*)&t[spx * 72 + q * 16];
    *(uint4*)(dst + 8) = *(const uint4*)&t[spx * 72 + q * 16 + 8];
}

// ---------------------------------------------------------------------------
// conv1 via MFMA, double-buffered pipelined staging (r13-exact).
// xb NHWC bf16 -> h NHWC bf16 (+bias+relu). Block 128px x 64o, 4 waves.
// ---------------------------------------------------------------------------
__global__ __launch_bounds__(256, 4) void conv1_mfma(const unsigned short* __restrict__ xb,
                                                     const unsigned short* __restrict__ wdcb,
                                                     const float* __restrict__ bias,
                                                     unsigned short* __restrict__ h) {
    __shared__ __align__(16) unsigned short sA[2][130 * 72];   // 37.4KB

    int tid = threadIdx.x;
    int linear = (blockIdx.x & 7) * 128 + (blockIdx.x >> 3);   // XCD swizzle, 1024 blocks
    int bx = linear & 1;
    int y  = (linear >> 1) & 255;
    int b  = linear >> 9;
    int X0 = bx * 128;

    int wave = tid >> 6, lane = tid & 63;
    int lr = lane & 15, lg = lane >> 4;
    int n0 = wave * 16;

    f32x4 acc[8];
#pragma unroll
    for (int m = 0; m < 8; ++m) { acc[m][0]=0.f; acc[m][1]=0.f; acc[m][2]=0.f; acc[m][3]=0.f; }

    const unsigned short* xbb = xb + (long)b * HW_ * 64;
    const unsigned short* pb  = wdcb + (n0 + lr) * 64 + lg * 8;

    int r0 = (y == 0) ? 1 : 0;
    int r1 = (y == H_ - 1) ? 1 : 2;

    uint4 L[5];
    auto LOADROW = [&](int yr) {
        const unsigned short* src = xbb + (long)yr * (W_ * 64);
#pragma unroll
        for (int t = 0; t < 5; ++t) {
            int e = tid + t * 256;
            uint4 v = { 0u, 0u, 0u, 0u };
            if (e < 1040) {
                int col = X0 - 1 + (e >> 3);
                if (col >= 0 && col < W_)
                    v = *(const uint4*)&src[(long)col * 64 + (e & 7) * 8];
            }
            L[t] = v;
        }
    };

    LOADROW(y + r0 - 1);
    int pa = 0;
    for (int ky = r0; ky <= r1; ++ky, ++pa) {
        unsigned short* buf = sA[pa & 1];
#pragma unroll
        for (int t = 0; t < 5; ++t) {           // ds_write staged regs
            int e = tid + t * 256;
            if (e < 1040) *(uint4*)&buf[(e >> 3) * 72 + (e & 7) * 8] = L[t];
        }
        if (ky < r1) LOADROW(y + ky);           // next row flies over MFMA
        asm volatile("s_waitcnt lgkmcnt(0)" ::: "memory");
        __builtin_amdgcn_s_barrier();
        asm volatile("" ::: "memory");
#pragma unroll
        for (int kx = 0; kx < 3; ++kx) {
            int k = ky * 3 + kx;
            bf16x8 b0 = *(const bf16x8*)(pb + k * 4096);
            bf16x8 b1 = *(const bf16x8*)(pb + k * 4096 + 32);
#pragma unroll
            for (int m = 0; m < 8; ++m) {
                const unsigned short* ap = &buf[(m * 16 + lr + kx) * 72 + lg * 8];
                bf16x8 a0 = *(const bf16x8*)ap;
                bf16x8 a1 = *(const bf16x8*)(ap + 32);
                acc[m] = __builtin_amdgcn_mfma_f32_16x16x32_bf16(a0, b0, acc[m], 0, 0, 0);
                acc[m] = __builtin_amdgcn_mfma_f32_16x16x32_bf16(a1, b1, acc[m], 0, 0, 0);
            }
        }
    }

    // epilogue: bias+relu, repack via LDS (sA[0]) to NHWC bf16
    __syncthreads();
    float bv = bias[n0 + lr];
    unsigned short* cs = sA[0];
#pragma unroll
    for (int m = 0; m < 8; ++m)
#pragma unroll
        for (int r = 0; r < 4; ++r) {
            float vv = fmaxf(acc[m][r] + bv, 0.f);
            cs[(m * 16 + lg * 4 + r) * 72 + n0 + lr] = (unsigned short)f2bf(vv);
        }
    __syncthreads();
    int spx = tid >> 1, sc0 = (tid & 1) * 32;
    unsigned short* dst = h + ((long)b * HW_ + (long)y * W_ + X0 + spx) * 64 + sc0;
    const unsigned short* srcp = &cs[spx * 72 + sc0];
#pragma unroll
    for (int q = 0; q < 4; ++q)
        *(uint4*)(dst + q * 8) = *(const uint4*)(srcp + q * 8);
}

// ---------------------------------------------------------------------------
// conv2 via MFMA, double-buffered pipelined staging, N=18 padded to 32
// (r13-exact). h NHWC bf16 -> off NCHW f32. Block 128px x 32o, 4 waves.
// ---------------------------------------------------------------------------
__global__ __launch_bounds__(256, 4) void conv2_mfma(const unsigned short* __restrict__ h,
                                                     const unsigned short* __restrict__ woffb,
                                                     const float* __restrict__ bias,
                                                     float* __restrict__ off) {
    __shared__ __align__(16) unsigned short sA[2][130 * 72];

    int tid = threadIdx.x;
    int linear = (blockIdx.x & 7) * 128 + (blockIdx.x >> 3);   // 1024 blocks
    int bx = linear & 1;
    int y  = (linear >> 1) & 255;
    int b  = linear >> 9;
    int X0 = bx * 128;

    int wave = tid >> 6, lane = tid & 63;
    int lr = lane & 15, lg = lane >> 4;
    int pxh = wave & 1, nh = wave >> 1;
    int n0 = nh * 16;
    int pxb = pxh * 64;

    f32x4 acc[4];
#pragma unroll
    for (int m = 0; m < 4; ++m) { acc[m][0]=0.f; acc[m][1]=0.f; acc[m][2]=0.f; acc[m][3]=0.f; }

    const unsigned short* hb = h + (long)b * HW_ * 64;
    const unsigned short* pb = woffb + (n0 + lr) * 64 + lg * 8;

    int r0 = (y == 0) ? 1 : 0;
    int r1 = (y == H_ - 1) ? 1 : 2;

    uint4 L[5];
    auto LOADROW = [&](int yr) {
        const unsigned short* src = hb + (long)yr * (W_ * 64);
#pragma unroll
        for (int t = 0; t < 5; ++t) {
            int e = tid + t * 256;
            uint4 v = { 0u, 0u, 0u, 0u };
            if (e < 1040) {
                int col = X0 - 1 + (e >> 3);
                if (col >= 0 && col < W_)
                    v = *(const uint4*)&src[(long)col * 64 + (e & 7) * 8];
            }
            L[t] = v;
        }
    };

    LOADROW(y + r0 - 1);
    int pa = 0;
    for (int ky = r0; ky <= r1; ++ky, ++pa) {
        unsigned short* buf = sA[pa & 1];
#pragma unroll
        for (int t = 0; t < 5; ++t) {
            int e = tid + t * 256;
            if (e < 1040) *(uint4*)&buf[(e >> 3) * 72 + (e & 7) * 8] = L[t];
        }
        if (ky < r1) LOADROW(y + ky);
        asm volatile("s_waitcnt lgkmcnt(0)" ::: "memory");
        __builtin_amdgcn_s_barrier();
        asm volatile("" ::: "memory");
#pragma unroll
        for (int kx = 0; kx < 3; ++kx) {
            int k = ky * 3 + kx;
            bf16x8 b0 = *(const bf16x8*)(pb + k * 2048);
            bf16x8 b1 = *(const bf16x8*)(pb + k * 2048 + 32);
#pragma unroll
            for (int m = 0; m < 4; ++m) {
                const unsigned short* ap = &buf[(pxb + m * 16 + lr + kx) * 72 + lg * 8];
                bf16x8 a0 = *(const bf16x8*)ap;
                bf16x8 a1 = *(const bf16x8*)(ap + 32);
                acc[m] = __builtin_amdgcn_mfma_f32_16x16x32_bf16(a0, b0, acc[m], 0, 0, 0);
                acc[m] = __builtin_amdgcn_mfma_f32_16x16x32_bf16(a1, b1, acc[m], 0, 0, 0);
            }
        }
    }

    int o = n0 + lr;
    if (o < 18) {
        float bv = bias[o];
        float* op = off + ((long)b * 18 + o) * HW_ + (long)y * W_ + X0 + pxb;
#pragma unroll
        for (int m = 0; m < 4; ++m) {
            float4 r = { acc[m][0] + bv, acc[m][1] + bv, acc[m][2] + bv, acc[m][3] + bv };
            *(float4*)(op + m * 16 + lg * 4) = r;
        }
    }
}

// ---------------------------------------------------------------------------
// deform conv via MFMA — r19-exact (best measured: 47.5 µs, total 95.2):
// half-step gather prefetch (gathers for tap k+1 issued after the barrier,
// live only across the MFMA phase); weights loaded at loop-top (oldest VMEM
// -> MFMA's implicit vmcnt never drains gathers); channel-major gather;
// slot-XOR swizzled val LDS; lgkm-only barrier per tap; (256,5).
// ---------------------------------------------------------------------------
struct Pass16 {
    uint4 a00, a01, a10, a11;   // corners, chans c0..c0+8
    uint4 b00, b01, b10, b11;   // corners, chans c0+8..c0+16
    float w00, w01, w10, w11;
};

__device__ __forceinline__ Pass16 issue16(const unsigned short* __restrict__ hb,
                                          int k, int y, int px, float dy, float dx, int c0) {
    Pass16 s;
    float py  = (float)(y - 1 + k / 3) + dy;
    float pxs = (float)(px - 1 + k % 3) + dx;
    float y0f = floorf(py), x0f = floorf(pxs);
    int iy0 = (int)y0f, ix0 = (int)x0f;
    float wy1 = py - y0f, wx1 = pxs - x0f;
    float wy0 = 1.f - wy1, wx0 = 1.f - wx1;
    bool vy0 = (iy0 >= 0) && (iy0 < H_);
    bool vy1 = (iy0 >= -1) && (iy0 < H_ - 1);
    bool vx0 = (ix0 >= 0) && (ix0 < W_);
    bool vx1 = (ix0 >= -1) && (ix0 < W_ - 1);
    int cy0 = min(max(iy0, 0), H_ - 1), cy1 = min(max(iy0 + 1, 0), H_ - 1);
    int cx0 = min(max(ix0, 0), W_ - 1), cx1 = min(max(ix0 + 1, 0), W_ - 1);
    s.w00 = wy0 * wx0 * ((vy0 && vx0) ? 1.f : 0.f);
    s.w01 = wy0 * wx1 * ((vy0 && vx1) ? 1.f : 0.f);
    s.w10 = wy1 * wx0 * ((vy1 && vx0) ? 1.f : 0.f);
    s.w11 = wy1 * wx1 * ((vy1 && vx1) ? 1.f : 0.f);
    int r00 = (cy0 * W_ + cx0) * 64 + c0, r01 = (cy0 * W_ + cx1) * 64 + c0;
    int r10 = (cy1 * W_ + cx0) * 64 + c0, r11 = (cy1 * W_ + cx1) * 64 + c0;
    s.a00 = *(const uint4*)&hb[r00];     s.a01 = *(const uint4*)&hb[r01];
    s.a10 = *(const uint4*)&hb[r10];     s.a11 = *(const uint4*)&hb[r11];
    s.b00 = *(const uint4*)&hb[r00 + 8]; s.b01 = *(const uint4*)&hb[r01 + 8];
    s.b10 = *(const uint4*)&hb[r10 + 8]; s.b11 = *(const uint4*)&hb[r11 + 8];
    return s;
}

__device__ __forceinline__ uint4 interp8u(uint4 q0, uint4 q1, uint4 q2, uint4 q3,
                                          float w00, float w01, float w10, float w11) {
    float g0[8], g1[8], g2[8], g3[8];
    unpack8(q0, g0); unpack8(q1, g1); unpack8(q2, g2); unpack8(q3, g3);
    unsigned r[4];
#pragma unroll
    for (int j = 0; j < 4; ++j) {
        float lo = fmaf(g3[2*j],   w11, fmaf(g2[2*j],   w10, fmaf(g1[2*j],   w01, g0[2*j]   * w00)));
        float hi = fmaf(g3[2*j+1], w11, fmaf(g2[2*j+1], w10, fmaf(g1[2*j+1], w01, g0[2*j+1] * w00)));
        r[j] = cvtpk(lo, hi);
    }
    uint4 u = { r[0], r[1], r[2], r[3] };
    return u;
}

__global__ __launch_bounds__(256, 5) void deform_mfma(const unsigned short* __restrict__ h,
                                                      const float* __restrict__ off,
                                                      const unsigned short* __restrict__ wdefb,
                                                      const float* __restrict__ bias,
                                                      float* __restrict__ out) {
    __shared__ __align__(16) unsigned short val[2][64 * 64];   // 16KB double buffer

    int tid = threadIdx.x;
    int linear = (blockIdx.x & 7) * 256 + (blockIdx.x >> 3);   // 2048 blocks, XCD swizzle
    int b  = linear >> 10;
    int y  = (linear >> 2) & 255;
    int x0 = (linear & 3) * 64;

    int lane = tid & 63, wave = tid >> 6;
    int lr = lane & 15, lg = lane >> 4;
    int n0 = wave * 16;
    int gpx = tid >> 2;            // gather px 0..63 (channel-major: 4 lanes/pixel)
    int gc  = tid & 3;             // 16-chan chunk
    int c0  = gc * 16;
    int gx  = x0 + gpx;

    f32x4 acc[4];
#pragma unroll
    for (int m = 0; m < 4; ++m) { acc[m][0]=0.f; acc[m][1]=0.f; acc[m][2]=0.f; acc[m][3]=0.f; }

    const unsigned short* hb   = h + (long)b * HW_ * 64;
    const float* ofb  = off + (long)b * 18 * HW_ + y * W_ + gx;
    const unsigned short* bsrc = wdefb + (n0 + lr) * 64 + lg * 8;

    // prologue: tap-0 offsets + gathers; tap-1 offsets
    float dy0 = ofb[0], dx0 = ofb[HW_];
    Pass16 S = issue16(hb, 0, y, gx, dy0, dx0, c0);
    float dyn = ofb[2 * HW_], dxn = ofb[3 * HW_];

    // swizzled LDS slots (shorts): slot index 0..7 within a 128B px row
    int slotL = ((2 * gc)     ^ (gpx & 7)) * 8;
    int slotH = ((2 * gc + 1) ^ (gpx & 7)) * 8;
    int rdL   = ((lg)     ^ (lr & 7)) * 8;
    int rdH   = ((lg + 4) ^ (lr & 7)) * 8;

    for (int k = 0; k < 9; ++k) {
        // weights for tap k — issued FIRST (oldest VMEM this iteration), so the
        // MFMA's implicit vmcnt wait never drains the gathers issued below.
        bf16x8 bc0 = *(const bf16x8*)(bsrc + k * 4096);
        bf16x8 bc1 = *(const bf16x8*)(bsrc + k * 4096 + 32);

        // interp tap k (S's gathers: issued last iteration before MFMA(k-1),
        // latency partially hidden under that MFMA + this iteration's setup)
        unsigned short* vb = val[k & 1];
        *(uint4*)&vb[gpx * 64 + slotL] = interp8u(S.a00, S.a01, S.a10, S.a11,
                                                  S.w00, S.w01, S.w10, S.w11);
        *(uint4*)&vb[gpx * 64 + slotH] = interp8u(S.b00, S.b01, S.b10, S.b11,
                                                  S.w00, S.w01, S.w10, S.w11);

        asm volatile("s_waitcnt lgkmcnt(0)" ::: "memory");  // my ds_writes committed
        __builtin_amdgcn_s_barrier();                       // vmcnt NOT drained
        asm volatile("" ::: "memory");                      // keep ds_reads below barrier

        // issue gathers for tap k+1 + offsets for tap k+2 — held only across
        // the MFMA phase below, consumed by next iteration's interp.
        Pass16 S2;
        float dy3 = 0.f, dx3 = 0.f;
        if (k < 8) {
            S2 = issue16(hb, k + 1, y, gx, dyn, dxn, c0);
            if (k < 7) { dy3 = ofb[(2 * k + 4) * HW_]; dx3 = ofb[(2 * k + 5) * HW_]; }
        }
        __builtin_amdgcn_sched_barrier(0);                  // pin gather issue above MFMA

        __builtin_amdgcn_s_setprio(1);
#pragma unroll
        for (int m = 0; m < 4; ++m) {
            const unsigned short* ap = &vb[(m * 16 + lr) * 64];
            bf16x8 a0 = *(const bf16x8*)&ap[rdL];
            bf16x8 a1 = *(const bf16x8*)&ap[rdH];
            acc[m] = __builtin_amdgcn_mfma_f32_16x16x32_bf16(a0, bc0, acc[m], 0, 0, 0);
            acc[m] = __builtin_amdgcn_mfma_f32_16x16x32_bf16(a1, bc1, acc[m], 0, 0, 0);
        }
        __builtin_amdgcn_s_setprio(0);

        S = S2; dyn = dy3; dxn = dx3;
    }

    // epilogue: D col=lane&15 -> o = n0+lr; row -> px = m*16+lg*4+r
    float bv = bias[n0 + lr];
    float* outb = out + ((long)b * 64 + n0 + lr) * HW_ + y * W_ + x0;
#pragma unroll
    for (int m = 0; m < 4; ++m) {
        float4 r = { fmaxf(acc[m][0] + bv, 0.f), fmaxf(acc[m][1] + bv, 0.f),
                     fmaxf(acc[m][2] + bv, 0.f), fmaxf(acc[m][3] + bv, 0.f) };
        *(float4*)(outb + m * 16 + lg * 4) = r;
    }
}

// ---------------------------------------------------------------------------
extern "C" void kernel_launch(void* const* d_in, const int* in_sizes, int n_in,
                              void* d_out, int out_size, void* d_ws, size_t ws_size,
                              hipStream_t stream) {
    const float* x        = (const float*)d_in[0];
    const float* w_deconv = (const float*)d_in[1];
    const float* b_deconv = (const float*)d_in[2];
    const float* w_off    = (const float*)d_in[3];
    const float* b_off    = (const float*)d_in[4];
    const float* w_def    = (const float*)d_in[5];
    const float* b_def    = (const float*)d_in[6];
    float* out = (float*)d_out;

    char* ws = (char*)d_ws;
    unsigned short* xbb   = (unsigned short*)ws;               // 16,777,216 B
    unsigned short* hbf   = (unsigned short*)(ws + 16777216);  // 16,777,216 B
    float* offset         = (float*)(ws + 33554432);           //  9,437,184 B
    unsigned short* wdcb  = (unsigned short*)(ws + 42991616);  //     73,728 B
    unsigned short* wdefb = (unsigned short*)(ws + 43065344);  //     73,728 B
    unsigned short* woffb = (unsigned short*)(ws + 43139072);  //     36,864 B

    prep_weights<<<144, 256, 0, stream>>>(w_def, wdefb, w_deconv, wdcb, w_off, woffb);
    x_to_nhwc<<<2048, 256, 0, stream>>>(x, xbb);
    conv1_mfma<<<1024, 256, 0, stream>>>(xbb, wdcb, b_deconv, hbf);
    conv2_mfma<<<1024, 256, 0, stream>>>(hbf, woffb, b_off, offset);
    deform_mfma<<<2048, 256, 0, stream>>>(hbf, offset, wdefb, b_def, out);
}